// Round 3
// baseline (3249.052 us; speedup 1.0000x reference)
//
#include <hip/hip_runtime.h>

// ImageCaptionModel: B=128 T=32 V=10000 H=512 E=512 F=2048 NM=512
// Round 3: persistent recurrence kernel. 256 blocks x 256 thr, 128KB LDS each
// -> exactly 1 block/CU -> all blocks co-resident (no cooperative launch needed).
//   blocks  0..31 : stepB (layer1) persistent, W1 slice LDS-resident
//   blocks 32..63 : stepA (layer0) persistent, W0h slice LDS-resident
//   blocks 64..255: logits workers, tile schedule gated on flagB[t]
// Cross-step sync via device-scope atomic flags + threadfence (wbL2/inv).

typedef short s8v __attribute__((ext_vector_type(8)));   // 8 x bf16 bits
typedef float f4v __attribute__((ext_vector_type(4)));   // MFMA acc

__device__ __forceinline__ unsigned short f2bf(float f) {
  unsigned u = __float_as_uint(f);
  u += 0x7fffu + ((u >> 16) & 1u);          // round-to-nearest-even
  return (unsigned short)(u >> 16);
}
__device__ __forceinline__ float sigm(float x) { return 1.0f / (1.0f + __expf(-x)); }
__device__ __forceinline__ float tanh_(float x) { return 1.0f - 2.0f / (1.0f + __expf(2.0f * x)); }

__device__ __forceinline__ void glds16(const unsigned short* g, unsigned short* l) {
  __builtin_amdgcn_global_load_lds((const __attribute__((address_space(1))) void*)g,
                                   (__attribute__((address_space(3))) void*)l, 16, 0, 0);
}

// ---- flag sync: flags[0..31]=stepA done-count, flags[32..63]=stepB done-count
__device__ __forceinline__ void wait_ge(int* f, int n) {
  if (threadIdx.x == 0) {
    while (__hip_atomic_load(f, __ATOMIC_ACQUIRE, __HIP_MEMORY_SCOPE_AGENT) < n)
      __builtin_amdgcn_s_sleep(1);
  }
  __syncthreads();
  __threadfence();   // acquire: invalidate stale cache before data reads
}
__device__ __forceinline__ void signal_inc(int* f) {
  __threadfence();   // release: flush this thread's stores device-wide
  __syncthreads();
  if (threadIdx.x == 0)
    __hip_atomic_fetch_add(f, 1, __ATOMIC_RELEASE, __HIP_MEMORY_SCOPE_AGENT);
}

// ---- fused pre-work: 6 transposes + cnn cvt + emb gather + state init + flag zero
__global__ void k_prep(const float* __restrict__ W_in, const float* __restrict__ W0,
                       const float* __restrict__ W1, const float* __restrict__ W_out,
                       const float* __restrict__ cnn, const float* __restrict__ emb,
                       const int* __restrict__ tok, const float* __restrict__ chs,
                       unsigned short* __restrict__ Win_t, unsigned short* __restrict__ W0e_t,
                       unsigned short* __restrict__ W0m_t, unsigned short* __restrict__ W0h_t,
                       unsigned short* __restrict__ W1_t, unsigned short* __restrict__ Wout_t,
                       unsigned short* __restrict__ cnn_b, unsigned short* __restrict__ Xe,
                       unsigned short* __restrict__ h0b1, unsigned short* __restrict__ h1b1,
                       float* __restrict__ h0f, float* __restrict__ c0f,
                       float* __restrict__ h1f, float* __restrict__ c1f,
                       int* __restrict__ flags) {
  int blk = blockIdx.x;
  if (blk < 11152) {   // transpose jobs
    const float* src; unsigned short* dst; int R, C, bx, by;
    if (blk < 1024)      { src = W_in;             dst = Win_t;  R = 2048; C = 512;   bx = blk & 15; by = blk >> 4; }
    else if (blk < 2048) { int b2 = blk - 1024; src = W0;              dst = W0e_t;  R = 512;  C = 2048;  bx = b2 & 63; by = b2 >> 6; }
    else if (blk < 3072) { int b2 = blk - 2048; src = W0 + 512 * 2048; dst = W0m_t;  R = 512;  C = 2048;  bx = b2 & 63; by = b2 >> 6; }
    else if (blk < 4096) { int b2 = blk - 3072; src = W0 + 1024 * 2048; dst = W0h_t; R = 512;  C = 2048;  bx = b2 & 63; by = b2 >> 6; }
    else if (blk < 6144) { int b2 = blk - 4096; src = W1;              dst = W1_t;   R = 1024; C = 2048;  bx = b2 & 63; by = b2 >> 6; }
    else                 { int b2 = blk - 6144; src = W_out;           dst = Wout_t; R = 512;  C = 10000; bx = b2 % 313; by = b2 / 313; }
    __shared__ float tile[32][33];
    int c0 = bx * 32, r0 = by * 32;
    int tx = threadIdx.x, ty = threadIdx.y;
#pragma unroll
    for (int i = 0; i < 4; i++) {
      int r = r0 + ty + i * 8, c = c0 + tx;
      if (r < R && c < C) tile[ty + i * 8][tx] = src[(size_t)r * C + c];
    }
    __syncthreads();
#pragma unroll
    for (int i = 0; i < 4; i++) {
      int c = c0 + ty + i * 8, r = r0 + tx;
      if (r < R && c < C) dst[(size_t)c * R + r] = f2bf(tile[tx][ty + i * 8]);
    }
    return;
  }
  int ft = threadIdx.y * 32 + threadIdx.x;
  if (blk < 11408) {        // cnn fp32 -> bf16 (65536 float4s)
    int i = (blk - 11152) * 256 + ft;
    float4 v = ((const float4*)cnn)[i];
    ushort4 p; p.x = f2bf(v.x); p.y = f2bf(v.y); p.z = f2bf(v.z); p.w = f2bf(v.w);
    ((ushort4*)cnn_b)[i] = p;
  } else if (blk < 13456) { // embedding gather (524288 float4s)
    int i = (blk - 11408) * 256 + ft;
    int r = i >> 7, k4 = (i & 127) * 4;
    int b = r & 127, t = r >> 7;
    int tk = tok[b * 32 + t];
    float4 v = *(const float4*)(emb + (size_t)tk * 512 + k4);
    ushort4 p; p.x = f2bf(v.x); p.y = f2bf(v.y); p.z = f2bf(v.z); p.w = f2bf(v.w);
    ((ushort4*)Xe)[i] = p;
  } else if (blk < 13712) { // init h/c state (65536)
    int i = (blk - 13456) * 256 + ft;
    int b = i >> 9, jj = i & 511;
    float h0 = chs[b * 1024 + jj], c0v = chs[b * 1024 + 512 + jj];
    float h1 = chs[131072 + b * 1024 + jj], c1v = chs[131072 + b * 1024 + 512 + jj];
    h0f[i] = h0; c0f[i] = c0v; h1f[i] = h1; c1f[i] = c1v;
    h0b1[i] = f2bf(h0); h1b1[i] = f2bf(h1);
  } else {                  // zero sync flags
    if (ft < 64) flags[ft] = 0;
  }
}

// ---- generic 128x128-tile GEMM (pre-work): C = A[M][K] * Bt[N][K]^T (+epilogue)
// MODE 0: proc = leaky(acc+bias) -> outB ; MODE 1: Cf = acc+bias -> outF
// MODE 2: Zx = acc + add128[m&127][n] -> outF
template <int MODE>
__global__ __launch_bounds__(256, 2)
void k_gemm(const unsigned short* __restrict__ A, const unsigned short* __restrict__ Bt,
            const float* __restrict__ bias, const float* __restrict__ add128,
            float* __restrict__ outF, unsigned short* __restrict__ outB,
            int M, int N, int K) {
  __shared__ unsigned short As[4096];
  __shared__ unsigned short Bs[4096];
  int tid = threadIdx.x;
  int wave = tid >> 6, lane = tid & 63;
  int lr = lane & 15, lq = lane >> 4;
  int wm = (wave >> 1) * 64, wn = (wave & 1) * 64;
  int m0 = blockIdx.y * 128, n0 = blockIdx.x * 128;

  f4v acc[4][4];
  f4v zero = {0.0f, 0.0f, 0.0f, 0.0f};
#pragma unroll
  for (int i = 0; i < 4; i++)
#pragma unroll
    for (int j = 0; j < 4; j++) acc[i][j] = zero;

  int srow = tid >> 2, sofs = (tid & 3) * 8;
  int ar0 = m0 + srow, ar1 = ar0 + 64;
  int br0 = n0 + srow, br1 = br0 + 64;
  if (br0 >= N) br0 = N - 1;
  if (br1 >= N) br1 = N - 1;
  const unsigned short* Ag0 = A + (size_t)ar0 * K + sofs;
  const unsigned short* Ag1 = A + (size_t)ar1 * K + sofs;
  const unsigned short* Bg0 = Bt + (size_t)br0 * K + sofs;
  const unsigned short* Bg1 = Bt + (size_t)br1 * K + sofs;

  for (int k0 = 0; k0 < K; k0 += 32) {
    glds16(Ag0 + k0, &As[tid * 8]);
    glds16(Ag1 + k0, &As[2048 + tid * 8]);
    glds16(Bg0 + k0, &Bs[tid * 8]);
    glds16(Bg1 + k0, &Bs[2048 + tid * 8]);
    __syncthreads();
    s8v af[4], bfr[4];
#pragma unroll
    for (int i = 0; i < 4; i++) af[i] = *(const s8v*)&As[(wm + i * 16 + lr) * 32 + lq * 8];
#pragma unroll
    for (int i = 0; i < 4; i++) bfr[i] = *(const s8v*)&Bs[(wn + i * 16 + lr) * 32 + lq * 8];
#pragma unroll
    for (int i = 0; i < 4; i++)
#pragma unroll
      for (int j = 0; j < 4; j++)
        acc[i][j] = __builtin_amdgcn_mfma_f32_16x16x32_bf16(af[i], bfr[j], acc[i][j], 0, 0, 0);
    __syncthreads();
  }

#pragma unroll
  for (int i = 0; i < 4; i++) {
#pragma unroll
    for (int j = 0; j < 4; j++) {
      int nn = n0 + wn + j * 16 + lr;
      if (nn >= N) continue;
#pragma unroll
      for (int r = 0; r < 4; r++) {
        int mm = m0 + wm + i * 16 + lq * 4 + r;
        float v = acc[i][j][r];
        if (MODE == 0) {
          v += bias[nn];
          v = v > 0.0f ? v : 0.01f * v;
          outB[(size_t)mm * N + nn] = f2bf(v);
        } else if (MODE == 1) {
          v += bias[nn];
          outF[(size_t)mm * N + nn] = v;
        } else {
          v += add128[(size_t)(mm & 127) * N + nn];
          outF[(size_t)mm * N + nn] = v;
        }
      }
    }
  }
}

// ---- persistent recurrence + logits ----
__global__ __launch_bounds__(256, 1)
void k_persist(const unsigned short* __restrict__ W0h_t, const unsigned short* __restrict__ W1_t,
               const float* __restrict__ Zx, const float* __restrict__ b1,
               unsigned short* __restrict__ h0b0, unsigned short* __restrict__ h0b1,
               unsigned short* __restrict__ h1b0, unsigned short* __restrict__ h1b1,
               float* __restrict__ h0f, float* __restrict__ c0f,
               float* __restrict__ h1f, float* __restrict__ c1f,
               unsigned short* __restrict__ H1all,
               const unsigned short* __restrict__ Wout_t, const float* __restrict__ b_out,
               float* __restrict__ out, int* __restrict__ flags) {
  __shared__ __align__(16) unsigned short sh[65536];   // 128 KB -> 1 block/CU
  int bid = blockIdx.x;
  int tid = threadIdx.x, wave = tid >> 6, lane = tid & 63;
  int lr = lane & 15, lq = lane >> 4, lqo = lq * 8;
  f4v zero = {0.0f, 0.0f, 0.0f, 0.0f};

  if (bid < 32) {
    // ================= stepB: z1 = [h0n(t)|h1(t-1)] @ W1 + b1 =================
    int jt = bid;
    // stage W1 slice into LDS, layout [kc][g][lane] x 16B (conflict-free reads)
    for (int it = 0; it < 32; it++) {
      int idx = tid + it * 256;
      int kc = idx >> 8, g = (idx >> 6) & 3, ln = idx & 63;
      s8v v = *(const s8v*)(W1_t + (size_t)(g * 512 + jt * 16 + (ln & 15)) * 1024
                                   + kc * 32 + (ln >> 4) * 8);
      *(s8v*)&sh[(size_t)idx * 8] = v;
    }
    __syncthreads();
    int rb0 = wave * 32 + lr;
    int j = jt * 16 + lr;
    float bi = b1[j], bo = b1[512 + j], bff = b1[1024 + j], bc = b1[1536 + j];
    for (int t = 0; t < 32; t++) {
      wait_ge(&flags[t], 32);                    // stepA(t) done (h0n ready)
      if (t >= 1) wait_ge(&flags[32 + t - 1], 32);  // stepB(t-1) done (h1 ready + WAR)
      const unsigned short* h0r = (t & 1) ? h0b1 : h0b0;
      const unsigned short* h1r = (t & 1) ? h1b0 : h1b1;
      unsigned short* h1w = (t & 1) ? h1b1 : h1b0;
      f4v acc[2][4];
#pragma unroll
      for (int i = 0; i < 2; i++)
#pragma unroll
        for (int g = 0; g < 4; g++) acc[i][g] = zero;
      s8v a_s[8][2];    // depth-8 A ring (16 loads in flight)
      s8v b_s[4][4];    // depth-3-ahead B ring from LDS
      auto issueA = [&](int kc) {
        int kcl = kc < 32 ? kc : 31;
        int s = kc & 7;
        const unsigned short* base = (kcl < 16) ? h0r : (h1r - 512);
        const unsigned short* p = base + rb0 * 512 + kcl * 32 + lqo;
        a_s[s][0] = *(const s8v*)p;
        a_s[s][1] = *(const s8v*)(p + 8192);     // +16 rows
      };
      auto issueB = [&](int kc) {
        int kcl = kc < 32 ? kc : 31;
        int s = kc & 3;
        const unsigned short* base = &sh[kcl * 2048 + lane * 8];
        b_s[s][0] = *(const s8v*)(base);
        b_s[s][1] = *(const s8v*)(base + 512);
        b_s[s][2] = *(const s8v*)(base + 1024);
        b_s[s][3] = *(const s8v*)(base + 1536);
      };
#pragma unroll
      for (int s = 0; s < 8; s++) issueA(s);
#pragma unroll
      for (int s = 0; s < 3; s++) issueB(s);
#pragma unroll
      for (int kc = 0; kc < 32; kc++) {
        s8v a0 = a_s[kc & 7][0], a1 = a_s[kc & 7][1];
#pragma unroll
        for (int g = 0; g < 4; g++) {
          acc[0][g] = __builtin_amdgcn_mfma_f32_16x16x32_bf16(a0, b_s[kc & 3][g], acc[0][g], 0, 0, 0);
          acc[1][g] = __builtin_amdgcn_mfma_f32_16x16x32_bf16(a1, b_s[kc & 3][g], acc[1][g], 0, 0, 0);
        }
        issueB(kc + 3);
        issueA(kc + 8);
      }
#pragma unroll
      for (int i = 0; i < 2; i++)
#pragma unroll
        for (int r = 0; r < 4; r++) {
          int mm = wave * 32 + i * 16 + lq * 4 + r;
          int idx = mm * 512 + j;
          float cprev = c1f[idx];
          float iv = sigm(acc[i][0][r] + bi);
          float ov = sigm(acc[i][1][r] + bo);
          float fv = sigm(acc[i][2][r] + bff);
          float cv = tanh_(acc[i][3][r] + bc);
          float cn = fv * cprev + iv * cv;
          float hn = ov * tanh_(cn);
          c1f[idx] = cn; h1f[idx] = hn;
          unsigned short hb = f2bf(hn);
          h1w[idx] = hb;
          H1all[(size_t)(t * 128 + mm) * 512 + j] = hb;
        }
      signal_inc(&flags[32 + t]);
    }
  } else if (bid < 64) {
    // ================= stepA: z0 = Zx[t] + h0(t-1) @ W0h =================
    int jt = bid - 32;
    for (int it = 0; it < 16; it++) {
      int idx = tid + it * 256;
      int kc = idx >> 8, g = (idx >> 6) & 3, ln = idx & 63;
      s8v v = *(const s8v*)(W0h_t + (size_t)(g * 512 + jt * 16 + (ln & 15)) * 512
                                    + kc * 32 + (ln >> 4) * 8);
      *(s8v*)&sh[(size_t)idx * 8] = v;
    }
    __syncthreads();
    int rb0 = wave * 32 + lr;
    int j = jt * 16 + lr;
    for (int t = 0; t < 32; t++) {
      // prefetch Zx for this step (precomputed: no flag dependency)
      float zx[2][4][4];
      const float* zb = Zx + (size_t)t * 262144 + j;
#pragma unroll
      for (int i = 0; i < 2; i++)
#pragma unroll
        for (int g = 0; g < 4; g++)
#pragma unroll
          for (int r = 0; r < 4; r++)
            zx[i][g][r] = zb[(wave * 32 + i * 16 + lq * 4 + r) * 2048 + g * 512];
      if (t >= 1) wait_ge(&flags[t - 1], 32);       // h0(t-1) ready
      if (t >= 2) wait_ge(&flags[32 + t - 2], 32);  // WAR on h0buf parity
      const unsigned short* h0r = (t & 1) ? h0b0 : h0b1;
      unsigned short* h0w = (t & 1) ? h0b1 : h0b0;
      f4v acc[2][4];
#pragma unroll
      for (int i = 0; i < 2; i++)
#pragma unroll
        for (int g = 0; g < 4; g++) acc[i][g] = zero;
      s8v a_s[8][2];
      s8v b_s[4][4];
      auto issueA = [&](int kc) {
        int kcl = kc < 16 ? kc : 15;
        int s = kc & 7;
        const unsigned short* p = h0r + rb0 * 512 + kcl * 32 + lqo;
        a_s[s][0] = *(const s8v*)p;
        a_s[s][1] = *(const s8v*)(p + 8192);
      };
      auto issueB = [&](int kc) {
        int kcl = kc < 16 ? kc : 15;
        int s = kc & 3;
        const unsigned short* base = &sh[kcl * 2048 + lane * 8];
        b_s[s][0] = *(const s8v*)(base);
        b_s[s][1] = *(const s8v*)(base + 512);
        b_s[s][2] = *(const s8v*)(base + 1024);
        b_s[s][3] = *(const s8v*)(base + 1536);
      };
#pragma unroll
      for (int s = 0; s < 8; s++) issueA(s);
#pragma unroll
      for (int s = 0; s < 3; s++) issueB(s);
#pragma unroll
      for (int kc = 0; kc < 16; kc++) {
        s8v a0 = a_s[kc & 7][0], a1 = a_s[kc & 7][1];
#pragma unroll
        for (int g = 0; g < 4; g++) {
          acc[0][g] = __builtin_amdgcn_mfma_f32_16x16x32_bf16(a0, b_s[kc & 3][g], acc[0][g], 0, 0, 0);
          acc[1][g] = __builtin_amdgcn_mfma_f32_16x16x32_bf16(a1, b_s[kc & 3][g], acc[1][g], 0, 0, 0);
        }
        issueB(kc + 3);
        issueA(kc + 8);
      }
#pragma unroll
      for (int i = 0; i < 2; i++)
#pragma unroll
        for (int r = 0; r < 4; r++) {
          int mm = wave * 32 + i * 16 + lq * 4 + r;
          int idx = mm * 512 + j;
          float cprev = c0f[idx];
          float iv = sigm(acc[i][0][r] + zx[i][0][r]);
          float ov = sigm(acc[i][1][r] + zx[i][1][r]);
          float fv = sigm(acc[i][2][r] + zx[i][2][r]);
          float cv = tanh_(acc[i][3][r] + zx[i][3][r]);
          float cn = fv * cprev + iv * cv;
          float hn = ov * tanh_(cn);
          c0f[idx] = cn; h0f[idx] = hn;
          h0w[idx] = f2bf(hn);
        }
      signal_inc(&flags[t]);
    }
  } else {
    // ================= logits workers: out[(b*32+t)*10000+n] =================
    int ww = bid - 64;
    unsigned short* As = sh;            // 4096 shorts
    unsigned short* Bs = sh + 4096;     // 4096 shorts
    int wm = (wave >> 1) * 64, wn = (wave & 1) * 64;
    int srow = tid >> 2, sofs = (tid & 3) * 8;
    int lastt = -1;
    for (int q = ww; q < 2528; q += 192) {   // 32 t x 79 tiles, t-major
      int t = q / 79, nb = q - t * 79;
      if (t != lastt) { wait_ge(&flags[32 + t], 32); lastt = t; }
      int n0 = nb * 128;
      const unsigned short* A = H1all + (size_t)t * 65536;
      int br0 = n0 + srow, br1 = br0 + 64;
      if (br0 > 9999) br0 = 9999;
      if (br1 > 9999) br1 = 9999;
      const unsigned short* Ag0 = A + srow * 512 + sofs;
      const unsigned short* Ag1 = A + (srow + 64) * 512 + sofs;
      const unsigned short* Bg0 = Wout_t + (size_t)br0 * 512 + sofs;
      const unsigned short* Bg1 = Wout_t + (size_t)br1 * 512 + sofs;
      f4v acc[4][4];
#pragma unroll
      for (int i = 0; i < 4; i++)
#pragma unroll
        for (int jj = 0; jj < 4; jj++) acc[i][jj] = zero;
      for (int k0 = 0; k0 < 512; k0 += 32) {
        glds16(Ag0 + k0, &As[tid * 8]);
        glds16(Ag1 + k0, &As[2048 + tid * 8]);
        glds16(Bg0 + k0, &Bs[tid * 8]);
        glds16(Bg1 + k0, &Bs[2048 + tid * 8]);
        __syncthreads();
        s8v af[4], bfr[4];
#pragma unroll
        for (int i = 0; i < 4; i++) af[i] = *(const s8v*)&As[(wm + i * 16 + lr) * 32 + lq * 8];
#pragma unroll
        for (int i = 0; i < 4; i++) bfr[i] = *(const s8v*)&Bs[(wn + i * 16 + lr) * 32 + lq * 8];
#pragma unroll
        for (int i = 0; i < 4; i++)
#pragma unroll
          for (int jj = 0; jj < 4; jj++)
            acc[i][jj] = __builtin_amdgcn_mfma_f32_16x16x32_bf16(af[i], bfr[jj], acc[i][jj], 0, 0, 0);
        __syncthreads();
      }
#pragma unroll
      for (int i = 0; i < 4; i++) {
#pragma unroll
        for (int jj = 0; jj < 4; jj++) {
          int nn = n0 + wn + jj * 16 + lr;
          if (nn >= 10000) continue;
#pragma unroll
          for (int r = 0; r < 4; r++) {
            int mm = wm + i * 16 + lq * 4 + r;   // = batch index b
            out[(size_t)(mm * 32 + t) * 10000 + nn] = acc[i][jj][r] + b_out[nn];
          }
        }
      }
    }
  }
}

// ---- final hidden writeout: out[40960000 + (l*128+b)*1024 + j] ----
__global__ void k_write_hidden(const float* __restrict__ h0f, const float* __restrict__ c0f,
                               const float* __restrict__ h1f, const float* __restrict__ c1f,
                               float* __restrict__ out) {
  int idx = blockIdx.x * 256 + threadIdx.x;  // 262144
  int l = idx >> 17, rem = idx & 131071, b = rem >> 10, j = rem & 1023;
  const float* hs = l ? h1f : h0f;
  const float* cs = l ? c1f : c0f;
  float v = (j < 512) ? hs[b * 512 + j] : cs[b * 512 + (j - 512)];
  out[40960000 + idx] = v;
}

extern "C" void kernel_launch(void* const* d_in, const int* in_sizes, int n_in,
                              void* d_out, int out_size, void* d_ws, size_t ws_size,
                              hipStream_t stream) {
  const float* cnn  = (const float*)d_in[0];
  const int*   tok  = (const int*)d_in[1];
  const float* chs  = (const float*)d_in[2];
  const float* emb  = (const float*)d_in[3];
  const float* W_in = (const float*)d_in[4];
  const float* b_in = (const float*)d_in[5];
  const float* W0   = (const float*)d_in[6];
  const float* b0   = (const float*)d_in[7];
  const float* W1   = (const float*)d_in[8];
  const float* b1   = (const float*)d_in[9];
  const float* W_out= (const float*)d_in[10];
  const float* b_out= (const float*)d_in[11];
  float* out = (float*)d_out;

  char* p = (char*)d_ws;
  auto alloc = [&](size_t bytes) { char* q = p; p += (bytes + 255) & ~(size_t)255; return q; };
  unsigned short* Win_t  = (unsigned short*)alloc((size_t)512 * 2048 * 2);
  unsigned short* W0e_t  = (unsigned short*)alloc((size_t)2048 * 512 * 2);
  unsigned short* W0m_t  = (unsigned short*)alloc((size_t)2048 * 512 * 2);
  unsigned short* W0h_t  = (unsigned short*)alloc((size_t)2048 * 512 * 2);
  unsigned short* W1_t   = (unsigned short*)alloc((size_t)2048 * 1024 * 2);
  unsigned short* Wout_t = (unsigned short*)alloc((size_t)10000 * 512 * 2);
  unsigned short* cnn_b  = (unsigned short*)alloc((size_t)128 * 2048 * 2);
  unsigned short* proc_b = (unsigned short*)alloc((size_t)128 * 512 * 2);
  float*          Cf     = (float*)alloc((size_t)128 * 2048 * 4);
  unsigned short* Xe     = (unsigned short*)alloc((size_t)4096 * 512 * 2);
  float*          Zx     = (float*)alloc((size_t)4096 * 2048 * 4);
  unsigned short* h0b0   = (unsigned short*)alloc(65536 * 2);
  unsigned short* h0b1   = (unsigned short*)alloc(65536 * 2);
  unsigned short* h1b0   = (unsigned short*)alloc(65536 * 2);
  unsigned short* h1b1   = (unsigned short*)alloc(65536 * 2);
  float*          h0f    = (float*)alloc(65536 * 4);
  float*          c0f    = (float*)alloc(65536 * 4);
  float*          h1f    = (float*)alloc(65536 * 4);
  float*          c1f    = (float*)alloc(65536 * 4);
  unsigned short* H1all  = (unsigned short*)alloc((size_t)4096 * 512 * 2);
  int*            flags  = (int*)alloc(256);

  // 1) all pre-work in one launch
  k_prep<<<13713, dim3(32, 8), 0, stream>>>(W_in, W0, W1, W_out, cnn, emb, tok, chs,
                                            Win_t, W0e_t, W0m_t, W0h_t, W1_t, Wout_t,
                                            cnn_b, Xe, h0b1, h1b1, h0f, c0f, h1f, c1f, flags);
  // 2) proc = leaky(cnn @ W_in + b_in)
  k_gemm<0><<<dim3(4, 1), 256, 0, stream>>>(cnn_b, Win_t, b_in, nullptr, nullptr, proc_b,
                                            128, 512, 2048);
  // 3) Cf = proc @ W0[512:1024] + b0
  k_gemm<1><<<dim3(16, 1), 256, 0, stream>>>(proc_b, W0m_t, b0, nullptr, Cf, nullptr,
                                             128, 2048, 512);
  // 4) Zx[t*128+b] = emb_t @ W0[0:512] + Cf[b]
  k_gemm<2><<<dim3(16, 32), 256, 0, stream>>>(Xe, W0e_t, nullptr, Cf, Zx, nullptr,
                                              4096, 2048, 512);
  // 5) persistent recurrence + logits
  k_persist<<<256, 256, 0, stream>>>(W0h_t, W1_t, Zx, b1, h0b0, h0b1, h1b0, h1b1,
                                     h0f, c0f, h1f, c1f, H1all, Wout_t, b_out, out, flags);
  // 6) hidden-state writeout
  k_write_hidden<<<1024, 256, 0, stream>>>(h0f, c0f, h1f, c1f, out);
}

// Round 4
// 1050.914 us; speedup vs baseline: 3.0916x; 3.0916x over previous
//
#include <hip/hip_runtime.h>

// ImageCaptionModel: B=128 T=32 V=10000 H=512 E=512 F=2048 NM=512
// Round 4: persistent recurrence kernel (round-3 structure) with FIXED sync:
//   - spin on RELAXED agent-scope atomic loads (no cache maintenance per iter)
//   - exactly ONE acquire (buffer_inv) per wait, ONE release (wbl2) per signal
// Round 3's acquire-in-spin-loop + all-thread threadfences invalidated L2
// thousands of times per step -> 99% idle. This removes the fence storm.
//   blocks  0..31 : stepB (layer1) persistent, W1 slice LDS-resident
//   blocks 32..63 : stepA (layer0) persistent, W0h slice LDS-resident
//   blocks 64..255: logits workers, tile schedule gated on flagB[t]

typedef short s8v __attribute__((ext_vector_type(8)));   // 8 x bf16 bits
typedef float f4v __attribute__((ext_vector_type(4)));   // MFMA acc

__device__ __forceinline__ unsigned short f2bf(float f) {
  unsigned u = __float_as_uint(f);
  u += 0x7fffu + ((u >> 16) & 1u);          // round-to-nearest-even
  return (unsigned short)(u >> 16);
}
__device__ __forceinline__ float sigm(float x) { return 1.0f / (1.0f + __expf(-x)); }
__device__ __forceinline__ float tanh_(float x) { return 1.0f - 2.0f / (1.0f + __expf(2.0f * x)); }

__device__ __forceinline__ void glds16(const unsigned short* g, unsigned short* l) {
  __builtin_amdgcn_global_load_lds((const __attribute__((address_space(1))) void*)g,
                                   (__attribute__((address_space(3))) void*)l, 16, 0, 0);
}

// ---- flag sync: flags[0..31]=stepA done-count, flags[32..63]=stepB done-count
// wait: thread0 spins RELAXED (agent-scope load reads coherent point, no inv);
// after barrier, every thread does ONE acquire load -> per-wave buffer_inv
// orders that wave's subsequent data reads. signal: barrier drains all waves'
// stores (vmcnt0 before s_barrier), thread0's RELEASE fetch_add emits one wbl2.
__device__ __forceinline__ void wait_ge(int* f, int n) {
  if (threadIdx.x == 0) {
    while (__hip_atomic_load(f, __ATOMIC_RELAXED, __HIP_MEMORY_SCOPE_AGENT) < n) {}
  }
  __syncthreads();
  (void)__hip_atomic_load(f, __ATOMIC_ACQUIRE, __HIP_MEMORY_SCOPE_AGENT);
}
__device__ __forceinline__ void signal_inc(int* f) {
  __syncthreads();   // compiler emits s_waitcnt vmcnt(0) before s_barrier
  if (threadIdx.x == 0)
    __hip_atomic_fetch_add(f, 1, __ATOMIC_RELEASE, __HIP_MEMORY_SCOPE_AGENT);
}

// ---- fused pre-work: 6 transposes + cnn cvt + emb gather + state init + flag zero
__global__ void k_prep(const float* __restrict__ W_in, const float* __restrict__ W0,
                       const float* __restrict__ W1, const float* __restrict__ W_out,
                       const float* __restrict__ cnn, const float* __restrict__ emb,
                       const int* __restrict__ tok, const float* __restrict__ chs,
                       unsigned short* __restrict__ Win_t, unsigned short* __restrict__ W0e_t,
                       unsigned short* __restrict__ W0m_t, unsigned short* __restrict__ W0h_t,
                       unsigned short* __restrict__ W1_t, unsigned short* __restrict__ Wout_t,
                       unsigned short* __restrict__ cnn_b, unsigned short* __restrict__ Xe,
                       unsigned short* __restrict__ h0b1, unsigned short* __restrict__ h1b1,
                       float* __restrict__ h0f, float* __restrict__ c0f,
                       float* __restrict__ h1f, float* __restrict__ c1f,
                       int* __restrict__ flags) {
  int blk = blockIdx.x;
  if (blk < 11152) {   // transpose jobs
    const float* src; unsigned short* dst; int R, C, bx, by;
    if (blk < 1024)      { src = W_in;             dst = Win_t;  R = 2048; C = 512;   bx = blk & 15; by = blk >> 4; }
    else if (blk < 2048) { int b2 = blk - 1024; src = W0;              dst = W0e_t;  R = 512;  C = 2048;  bx = b2 & 63; by = b2 >> 6; }
    else if (blk < 3072) { int b2 = blk - 2048; src = W0 + 512 * 2048; dst = W0m_t;  R = 512;  C = 2048;  bx = b2 & 63; by = b2 >> 6; }
    else if (blk < 4096) { int b2 = blk - 3072; src = W0 + 1024 * 2048; dst = W0h_t; R = 512;  C = 2048;  bx = b2 & 63; by = b2 >> 6; }
    else if (blk < 6144) { int b2 = blk - 4096; src = W1;              dst = W1_t;   R = 1024; C = 2048;  bx = b2 & 63; by = b2 >> 6; }
    else                 { int b2 = blk - 6144; src = W_out;           dst = Wout_t; R = 512;  C = 10000; bx = b2 % 313; by = b2 / 313; }
    __shared__ float tile[32][33];
    int c0 = bx * 32, r0 = by * 32;
    int tx = threadIdx.x, ty = threadIdx.y;
#pragma unroll
    for (int i = 0; i < 4; i++) {
      int r = r0 + ty + i * 8, c = c0 + tx;
      if (r < R && c < C) tile[ty + i * 8][tx] = src[(size_t)r * C + c];
    }
    __syncthreads();
#pragma unroll
    for (int i = 0; i < 4; i++) {
      int c = c0 + ty + i * 8, r = r0 + tx;
      if (r < R && c < C) dst[(size_t)c * R + r] = f2bf(tile[tx][ty + i * 8]);
    }
    return;
  }
  int ft = threadIdx.y * 32 + threadIdx.x;
  if (blk < 11408) {        // cnn fp32 -> bf16 (65536 float4s)
    int i = (blk - 11152) * 256 + ft;
    float4 v = ((const float4*)cnn)[i];
    ushort4 p; p.x = f2bf(v.x); p.y = f2bf(v.y); p.z = f2bf(v.z); p.w = f2bf(v.w);
    ((ushort4*)cnn_b)[i] = p;
  } else if (blk < 13456) { // embedding gather (524288 float4s)
    int i = (blk - 11408) * 256 + ft;
    int r = i >> 7, k4 = (i & 127) * 4;
    int b = r & 127, t = r >> 7;
    int tk = tok[b * 32 + t];
    float4 v = *(const float4*)(emb + (size_t)tk * 512 + k4);
    ushort4 p; p.x = f2bf(v.x); p.y = f2bf(v.y); p.z = f2bf(v.z); p.w = f2bf(v.w);
    ((ushort4*)Xe)[i] = p;
  } else if (blk < 13712) { // init h/c state (65536)
    int i = (blk - 13456) * 256 + ft;
    int b = i >> 9, jj = i & 511;
    float h0 = chs[b * 1024 + jj], c0v = chs[b * 1024 + 512 + jj];
    float h1 = chs[131072 + b * 1024 + jj], c1v = chs[131072 + b * 1024 + 512 + jj];
    h0f[i] = h0; c0f[i] = c0v; h1f[i] = h1; c1f[i] = c1v;
    h0b1[i] = f2bf(h0); h1b1[i] = f2bf(h1);
  } else {                  // zero sync flags
    if (ft < 64) flags[ft] = 0;
  }
}

// ---- generic 128x128-tile GEMM (pre-work): C = A[M][K] * Bt[N][K]^T (+epilogue)
// MODE 0: proc = leaky(acc+bias) -> outB ; MODE 1: Cf = acc+bias -> outF
// MODE 2: Zx = acc + add128[m&127][n] -> outF
template <int MODE>
__global__ __launch_bounds__(256, 2)
void k_gemm(const unsigned short* __restrict__ A, const unsigned short* __restrict__ Bt,
            const float* __restrict__ bias, const float* __restrict__ add128,
            float* __restrict__ outF, unsigned short* __restrict__ outB,
            int M, int N, int K) {
  __shared__ unsigned short As[4096];
  __shared__ unsigned short Bs[4096];
  int tid = threadIdx.x;
  int wave = tid >> 6, lane = tid & 63;
  int lr = lane & 15, lq = lane >> 4;
  int wm = (wave >> 1) * 64, wn = (wave & 1) * 64;
  int m0 = blockIdx.y * 128, n0 = blockIdx.x * 128;

  f4v acc[4][4];
  f4v zero = {0.0f, 0.0f, 0.0f, 0.0f};
#pragma unroll
  for (int i = 0; i < 4; i++)
#pragma unroll
    for (int j = 0; j < 4; j++) acc[i][j] = zero;

  int srow = tid >> 2, sofs = (tid & 3) * 8;
  int ar0 = m0 + srow, ar1 = ar0 + 64;
  int br0 = n0 + srow, br1 = br0 + 64;
  if (br0 >= N) br0 = N - 1;
  if (br1 >= N) br1 = N - 1;
  const unsigned short* Ag0 = A + (size_t)ar0 * K + sofs;
  const unsigned short* Ag1 = A + (size_t)ar1 * K + sofs;
  const unsigned short* Bg0 = Bt + (size_t)br0 * K + sofs;
  const unsigned short* Bg1 = Bt + (size_t)br1 * K + sofs;

  for (int k0 = 0; k0 < K; k0 += 32) {
    glds16(Ag0 + k0, &As[tid * 8]);
    glds16(Ag1 + k0, &As[2048 + tid * 8]);
    glds16(Bg0 + k0, &Bs[tid * 8]);
    glds16(Bg1 + k0, &Bs[2048 + tid * 8]);
    __syncthreads();
    s8v af[4], bfr[4];
#pragma unroll
    for (int i = 0; i < 4; i++) af[i] = *(const s8v*)&As[(wm + i * 16 + lr) * 32 + lq * 8];
#pragma unroll
    for (int i = 0; i < 4; i++) bfr[i] = *(const s8v*)&Bs[(wn + i * 16 + lr) * 32 + lq * 8];
#pragma unroll
    for (int i = 0; i < 4; i++)
#pragma unroll
      for (int j = 0; j < 4; j++)
        acc[i][j] = __builtin_amdgcn_mfma_f32_16x16x32_bf16(af[i], bfr[j], acc[i][j], 0, 0, 0);
    __syncthreads();
  }

#pragma unroll
  for (int i = 0; i < 4; i++) {
#pragma unroll
    for (int j = 0; j < 4; j++) {
      int nn = n0 + wn + j * 16 + lr;
      if (nn >= N) continue;
#pragma unroll
      for (int r = 0; r < 4; r++) {
        int mm = m0 + wm + i * 16 + lq * 4 + r;
        float v = acc[i][j][r];
        if (MODE == 0) {
          v += bias[nn];
          v = v > 0.0f ? v : 0.01f * v;
          outB[(size_t)mm * N + nn] = f2bf(v);
        } else if (MODE == 1) {
          v += bias[nn];
          outF[(size_t)mm * N + nn] = v;
        } else {
          v += add128[(size_t)(mm & 127) * N + nn];
          outF[(size_t)mm * N + nn] = v;
        }
      }
    }
  }
}

// ---- persistent recurrence + logits ----
__global__ __launch_bounds__(256, 1)
void k_persist(const unsigned short* __restrict__ W0h_t, const unsigned short* __restrict__ W1_t,
               const float* __restrict__ Zx, const float* __restrict__ b1,
               unsigned short* __restrict__ h0b0, unsigned short* __restrict__ h0b1,
               unsigned short* __restrict__ h1b0, unsigned short* __restrict__ h1b1,
               float* __restrict__ h0f, float* __restrict__ c0f,
               float* __restrict__ h1f, float* __restrict__ c1f,
               unsigned short* __restrict__ H1all,
               const unsigned short* __restrict__ Wout_t, const float* __restrict__ b_out,
               float* __restrict__ out, int* __restrict__ flags) {
  __shared__ __align__(16) unsigned short sh[65536];   // 128 KB -> 1 block/CU
  int bid = blockIdx.x;
  int tid = threadIdx.x, wave = tid >> 6, lane = tid & 63;
  int lr = lane & 15, lq = lane >> 4, lqo = lq * 8;
  f4v zero = {0.0f, 0.0f, 0.0f, 0.0f};

  if (bid < 32) {
    // ================= stepB: z1 = [h0n(t)|h1(t-1)] @ W1 + b1 =================
    int jt = bid;
    // stage W1 slice into LDS, layout [kc][g][lane] x 16B (conflict-free reads)
    for (int it = 0; it < 32; it++) {
      int idx = tid + it * 256;
      int kc = idx >> 8, g = (idx >> 6) & 3, ln = idx & 63;
      s8v v = *(const s8v*)(W1_t + (size_t)(g * 512 + jt * 16 + (ln & 15)) * 1024
                                   + kc * 32 + (ln >> 4) * 8);
      *(s8v*)&sh[(size_t)idx * 8] = v;
    }
    __syncthreads();
    int rb0 = wave * 32 + lr;
    int j = jt * 16 + lr;
    float bi = b1[j], bo = b1[512 + j], bff = b1[1024 + j], bc = b1[1536 + j];
    for (int t = 0; t < 32; t++) {
      wait_ge(&flags[t], 32);                    // stepA(t) done (h0n ready)
      if (t >= 1) wait_ge(&flags[32 + t - 1], 32);  // stepB(t-1) done (h1 ready + WAR)
      const unsigned short* h0r = (t & 1) ? h0b1 : h0b0;
      const unsigned short* h1r = (t & 1) ? h1b0 : h1b1;
      unsigned short* h1w = (t & 1) ? h1b1 : h1b0;
      f4v acc[2][4];
#pragma unroll
      for (int i = 0; i < 2; i++)
#pragma unroll
        for (int g = 0; g < 4; g++) acc[i][g] = zero;
      s8v a_s[8][2];    // depth-8 A ring (16 loads in flight)
      s8v b_s[4][4];    // depth-3-ahead B ring from LDS
      auto issueA = [&](int kc) {
        int kcl = kc < 32 ? kc : 31;
        int s = kc & 7;
        const unsigned short* base = (kcl < 16) ? h0r : (h1r - 512);
        const unsigned short* p = base + rb0 * 512 + kcl * 32 + lqo;
        a_s[s][0] = *(const s8v*)p;
        a_s[s][1] = *(const s8v*)(p + 8192);     // +16 rows
      };
      auto issueB = [&](int kc) {
        int kcl = kc < 32 ? kc : 31;
        int s = kc & 3;
        const unsigned short* base = &sh[kcl * 2048 + lane * 8];
        b_s[s][0] = *(const s8v*)(base);
        b_s[s][1] = *(const s8v*)(base + 512);
        b_s[s][2] = *(const s8v*)(base + 1024);
        b_s[s][3] = *(const s8v*)(base + 1536);
      };
#pragma unroll
      for (int s = 0; s < 8; s++) issueA(s);
#pragma unroll
      for (int s = 0; s < 3; s++) issueB(s);
#pragma unroll
      for (int kc = 0; kc < 32; kc++) {
        s8v a0 = a_s[kc & 7][0], a1 = a_s[kc & 7][1];
#pragma unroll
        for (int g = 0; g < 4; g++) {
          acc[0][g] = __builtin_amdgcn_mfma_f32_16x16x32_bf16(a0, b_s[kc & 3][g], acc[0][g], 0, 0, 0);
          acc[1][g] = __builtin_amdgcn_mfma_f32_16x16x32_bf16(a1, b_s[kc & 3][g], acc[1][g], 0, 0, 0);
        }
        issueB(kc + 3);
        issueA(kc + 8);
      }
#pragma unroll
      for (int i = 0; i < 2; i++)
#pragma unroll
        for (int r = 0; r < 4; r++) {
          int mm = wave * 32 + i * 16 + lq * 4 + r;
          int idx = mm * 512 + j;
          float cprev = c1f[idx];
          float iv = sigm(acc[i][0][r] + bi);
          float ov = sigm(acc[i][1][r] + bo);
          float fv = sigm(acc[i][2][r] + bff);
          float cv = tanh_(acc[i][3][r] + bc);
          float cn = fv * cprev + iv * cv;
          float hn = ov * tanh_(cn);
          c1f[idx] = cn; h1f[idx] = hn;
          unsigned short hb = f2bf(hn);
          h1w[idx] = hb;
          H1all[(size_t)(t * 128 + mm) * 512 + j] = hb;
        }
      signal_inc(&flags[32 + t]);
    }
  } else if (bid < 64) {
    // ================= stepA: z0 = Zx[t] + h0(t-1) @ W0h =================
    int jt = bid - 32;
    for (int it = 0; it < 16; it++) {
      int idx = tid + it * 256;
      int kc = idx >> 8, g = (idx >> 6) & 3, ln = idx & 63;
      s8v v = *(const s8v*)(W0h_t + (size_t)(g * 512 + jt * 16 + (ln & 15)) * 512
                                    + kc * 32 + (ln >> 4) * 8);
      *(s8v*)&sh[(size_t)idx * 8] = v;
    }
    __syncthreads();
    int rb0 = wave * 32 + lr;
    int j = jt * 16 + lr;
    for (int t = 0; t < 32; t++) {
      // prefetch Zx for this step (precomputed: no flag dependency)
      float zx[2][4][4];
      const float* zb = Zx + (size_t)t * 262144 + j;
#pragma unroll
      for (int i = 0; i < 2; i++)
#pragma unroll
        for (int g = 0; g < 4; g++)
#pragma unroll
          for (int r = 0; r < 4; r++)
            zx[i][g][r] = zb[(wave * 32 + i * 16 + lq * 4 + r) * 2048 + g * 512];
      if (t >= 1) wait_ge(&flags[t - 1], 32);       // h0(t-1) ready
      if (t >= 2) wait_ge(&flags[32 + t - 2], 32);  // WAR on h0buf parity
      const unsigned short* h0r = (t & 1) ? h0b0 : h0b1;
      unsigned short* h0w = (t & 1) ? h0b1 : h0b0;
      f4v acc[2][4];
#pragma unroll
      for (int i = 0; i < 2; i++)
#pragma unroll
        for (int g = 0; g < 4; g++) acc[i][g] = zero;
      s8v a_s[8][2];
      s8v b_s[4][4];
      auto issueA = [&](int kc) {
        int kcl = kc < 16 ? kc : 15;
        int s = kc & 7;
        const unsigned short* p = h0r + rb0 * 512 + kcl * 32 + lqo;
        a_s[s][0] = *(const s8v*)p;
        a_s[s][1] = *(const s8v*)(p + 8192);
      };
      auto issueB = [&](int kc) {
        int kcl = kc < 16 ? kc : 15;
        int s = kc & 3;
        const unsigned short* base = &sh[kcl * 2048 + lane * 8];
        b_s[s][0] = *(const s8v*)(base);
        b_s[s][1] = *(const s8v*)(base + 512);
        b_s[s][2] = *(const s8v*)(base + 1024);
        b_s[s][3] = *(const s8v*)(base + 1536);
      };
#pragma unroll
      for (int s = 0; s < 8; s++) issueA(s);
#pragma unroll
      for (int s = 0; s < 3; s++) issueB(s);
#pragma unroll
      for (int kc = 0; kc < 16; kc++) {
        s8v a0 = a_s[kc & 7][0], a1 = a_s[kc & 7][1];
#pragma unroll
        for (int g = 0; g < 4; g++) {
          acc[0][g] = __builtin_amdgcn_mfma_f32_16x16x32_bf16(a0, b_s[kc & 3][g], acc[0][g], 0, 0, 0);
          acc[1][g] = __builtin_amdgcn_mfma_f32_16x16x32_bf16(a1, b_s[kc & 3][g], acc[1][g], 0, 0, 0);
        }
        issueB(kc + 3);
        issueA(kc + 8);
      }
#pragma unroll
      for (int i = 0; i < 2; i++)
#pragma unroll
        for (int r = 0; r < 4; r++) {
          int mm = wave * 32 + i * 16 + lq * 4 + r;
          int idx = mm * 512 + j;
          float cprev = c0f[idx];
          float iv = sigm(acc[i][0][r] + zx[i][0][r]);
          float ov = sigm(acc[i][1][r] + zx[i][1][r]);
          float fv = sigm(acc[i][2][r] + zx[i][2][r]);
          float cv = tanh_(acc[i][3][r] + zx[i][3][r]);
          float cn = fv * cprev + iv * cv;
          float hn = ov * tanh_(cn);
          c0f[idx] = cn; h0f[idx] = hn;
          h0w[idx] = f2bf(hn);
        }
      signal_inc(&flags[t]);
    }
  } else {
    // ================= logits workers: out[(b*32+t)*10000+n] =================
    int ww = bid - 64;
    unsigned short* As = sh;            // 4096 shorts
    unsigned short* Bs = sh + 4096;     // 4096 shorts
    int wm = (wave >> 1) * 64, wn = (wave & 1) * 64;
    int srow = tid >> 2, sofs = (tid & 3) * 8;
    int lastt = -1;
    for (int q = ww; q < 2528; q += 192) {   // 32 t x 79 tiles, t-major
      int t = q / 79, nb = q - t * 79;
      if (t != lastt) { wait_ge(&flags[32 + t], 32); lastt = t; }
      int n0 = nb * 128;
      const unsigned short* A = H1all + (size_t)t * 65536;
      int br0 = n0 + srow, br1 = br0 + 64;
      if (br0 > 9999) br0 = 9999;
      if (br1 > 9999) br1 = 9999;
      const unsigned short* Ag0 = A + srow * 512 + sofs;
      const unsigned short* Ag1 = A + (srow + 64) * 512 + sofs;
      const unsigned short* Bg0 = Wout_t + (size_t)br0 * 512 + sofs;
      const unsigned short* Bg1 = Wout_t + (size_t)br1 * 512 + sofs;
      f4v acc[4][4];
#pragma unroll
      for (int i = 0; i < 4; i++)
#pragma unroll
        for (int jj = 0; jj < 4; jj++) acc[i][jj] = zero;
      for (int k0 = 0; k0 < 512; k0 += 32) {
        glds16(Ag0 + k0, &As[tid * 8]);
        glds16(Ag1 + k0, &As[2048 + tid * 8]);
        glds16(Bg0 + k0, &Bs[tid * 8]);
        glds16(Bg1 + k0, &Bs[2048 + tid * 8]);
        __syncthreads();
        s8v af[4], bfr[4];
#pragma unroll
        for (int i = 0; i < 4; i++) af[i] = *(const s8v*)&As[(wm + i * 16 + lr) * 32 + lq * 8];
#pragma unroll
        for (int i = 0; i < 4; i++) bfr[i] = *(const s8v*)&Bs[(wn + i * 16 + lr) * 32 + lq * 8];
#pragma unroll
        for (int i = 0; i < 4; i++)
#pragma unroll
          for (int jj = 0; jj < 4; jj++)
            acc[i][jj] = __builtin_amdgcn_mfma_f32_16x16x32_bf16(af[i], bfr[jj], acc[i][jj], 0, 0, 0);
        __syncthreads();
      }
#pragma unroll
      for (int i = 0; i < 4; i++) {
#pragma unroll
        for (int jj = 0; jj < 4; jj++) {
          int nn = n0 + wn + jj * 16 + lr;
          if (nn >= 10000) continue;
#pragma unroll
          for (int r = 0; r < 4; r++) {
            int mm = wm + i * 16 + lq * 4 + r;   // = batch index b
            out[(size_t)(mm * 32 + t) * 10000 + nn] = acc[i][jj][r] + b_out[nn];
          }
        }
      }
    }
  }
}

// ---- final hidden writeout: out[40960000 + (l*128+b)*1024 + j] ----
__global__ void k_write_hidden(const float* __restrict__ h0f, const float* __restrict__ c0f,
                               const float* __restrict__ h1f, const float* __restrict__ c1f,
                               float* __restrict__ out) {
  int idx = blockIdx.x * 256 + threadIdx.x;  // 262144
  int l = idx >> 17, rem = idx & 131071, b = rem >> 10, j = rem & 1023;
  const float* hs = l ? h1f : h0f;
  const float* cs = l ? c1f : c0f;
  float v = (j < 512) ? hs[b * 512 + j] : cs[b * 512 + (j - 512)];
  out[40960000 + idx] = v;
}

extern "C" void kernel_launch(void* const* d_in, const int* in_sizes, int n_in,
                              void* d_out, int out_size, void* d_ws, size_t ws_size,
                              hipStream_t stream) {
  const float* cnn  = (const float*)d_in[0];
  const int*   tok  = (const int*)d_in[1];
  const float* chs  = (const float*)d_in[2];
  const float* emb  = (const float*)d_in[3];
  const float* W_in = (const float*)d_in[4];
  const float* b_in = (const float*)d_in[5];
  const float* W0   = (const float*)d_in[6];
  const float* b0   = (const float*)d_in[7];
  const float* W1   = (const float*)d_in[8];
  const float* b1   = (const float*)d_in[9];
  const float* W_out= (const float*)d_in[10];
  const float* b_out= (const float*)d_in[11];
  float* out = (float*)d_out;

  char* p = (char*)d_ws;
  auto alloc = [&](size_t bytes) { char* q = p; p += (bytes + 255) & ~(size_t)255; return q; };
  unsigned short* Win_t  = (unsigned short*)alloc((size_t)512 * 2048 * 2);
  unsigned short* W0e_t  = (unsigned short*)alloc((size_t)2048 * 512 * 2);
  unsigned short* W0m_t  = (unsigned short*)alloc((size_t)2048 * 512 * 2);
  unsigned short* W0h_t  = (unsigned short*)alloc((size_t)2048 * 512 * 2);
  unsigned short* W1_t   = (unsigned short*)alloc((size_t)2048 * 1024 * 2);
  unsigned short* Wout_t = (unsigned short*)alloc((size_t)10000 * 512 * 2);
  unsigned short* cnn_b  = (unsigned short*)alloc((size_t)128 * 2048 * 2);
  unsigned short* proc_b = (unsigned short*)alloc((size_t)128 * 512 * 2);
  float*          Cf     = (float*)alloc((size_t)128 * 2048 * 4);
  unsigned short* Xe     = (unsigned short*)alloc((size_t)4096 * 512 * 2);
  float*          Zx     = (float*)alloc((size_t)4096 * 2048 * 4);
  unsigned short* h0b0   = (unsigned short*)alloc(65536 * 2);
  unsigned short* h0b1   = (unsigned short*)alloc(65536 * 2);
  unsigned short* h1b0   = (unsigned short*)alloc(65536 * 2);
  unsigned short* h1b1   = (unsigned short*)alloc(65536 * 2);
  float*          h0f    = (float*)alloc(65536 * 4);
  float*          c0f    = (float*)alloc(65536 * 4);
  float*          h1f    = (float*)alloc(65536 * 4);
  float*          c1f    = (float*)alloc(65536 * 4);
  unsigned short* H1all  = (unsigned short*)alloc((size_t)4096 * 512 * 2);
  int*            flags  = (int*)alloc(256);

  // 1) all pre-work in one launch
  k_prep<<<13713, dim3(32, 8), 0, stream>>>(W_in, W0, W1, W_out, cnn, emb, tok, chs,
                                            Win_t, W0e_t, W0m_t, W0h_t, W1_t, Wout_t,
                                            cnn_b, Xe, h0b1, h1b1, h0f, c0f, h1f, c1f, flags);
  // 2) proc = leaky(cnn @ W_in + b_in)
  k_gemm<0><<<dim3(4, 1), 256, 0, stream>>>(cnn_b, Win_t, b_in, nullptr, nullptr, proc_b,
                                            128, 512, 2048);
  // 3) Cf = proc @ W0[512:1024] + b0
  k_gemm<1><<<dim3(16, 1), 256, 0, stream>>>(proc_b, W0m_t, b0, nullptr, Cf, nullptr,
                                             128, 2048, 512);
  // 4) Zx[t*128+b] = emb_t @ W0[0:512] + Cf[b]
  k_gemm<2><<<dim3(16, 32), 256, 0, stream>>>(Xe, W0e_t, nullptr, Cf, Zx, nullptr,
                                              4096, 2048, 512);
  // 5) persistent recurrence + logits
  k_persist<<<256, 256, 0, stream>>>(W0h_t, W1_t, Zx, b1, h0b0, h0b1, h1b0, h1b1,
                                     h0f, c0f, h1f, c1f, H1all, Wout_t, b_out, out, flags);
  // 6) hidden-state writeout
  k_write_hidden<<<1024, 256, 0, stream>>>(h0f, c0f, h1f, c1f, out);
}

// Round 6
// 869.482 us; speedup vs baseline: 3.7368x; 1.2087x over previous
//
#include <hip/hip_runtime.h>

// ImageCaptionModel: B=128 T=32 V=10000 H=512 E=512 F=2048 NM=512
// Round 6: multi-launch recurrence (robust kernel-boundary sync, no atomics)
// with jt-owned phase blocks: 64 blocks x 256 thr; each block owns one jt
// column-slice and stages its W1/W0h slice into LDS ONCE per launch via
// global_load_lds. B-traffic per step: 48MB (LLC, round-2 scatter) -> 6MB.
// A/h re-reads now fit per-XCD L2 (~1.5MB working set < 4MB).
//   blocks  0..31: stepB(tB) jt-slice   blocks 32..63: stepA(tA) jt-slice

typedef short s8v __attribute__((ext_vector_type(8)));   // 8 x bf16 bits
typedef float f4v __attribute__((ext_vector_type(4)));   // MFMA acc

__device__ __forceinline__ unsigned short f2bf(float f) {
  unsigned u = __float_as_uint(f);
  u += 0x7fffu + ((u >> 16) & 1u);          // round-to-nearest-even
  return (unsigned short)(u >> 16);
}
__device__ __forceinline__ float sigm(float x) { return 1.0f / (1.0f + __expf(-x)); }
__device__ __forceinline__ float tanh_(float x) { return 1.0f - 2.0f / (1.0f + __expf(2.0f * x)); }

__device__ __forceinline__ void glds16(const unsigned short* g, unsigned short* l) {
  __builtin_amdgcn_global_load_lds((const __attribute__((address_space(1))) void*)g,
                                   (__attribute__((address_space(3))) void*)l, 16, 0, 0);
}

// ---- fused pre-work: 6 transposes + cnn cvt + emb gather + state init ----
__global__ void k_prep(const float* __restrict__ W_in, const float* __restrict__ W0,
                       const float* __restrict__ W1, const float* __restrict__ W_out,
                       const float* __restrict__ cnn, const float* __restrict__ emb,
                       const int* __restrict__ tok, const float* __restrict__ chs,
                       unsigned short* __restrict__ Win_t, unsigned short* __restrict__ W0e_t,
                       unsigned short* __restrict__ W0m_t, unsigned short* __restrict__ W0h_t,
                       unsigned short* __restrict__ W1_t, unsigned short* __restrict__ Wout_t,
                       unsigned short* __restrict__ cnn_b, unsigned short* __restrict__ Xe,
                       unsigned short* __restrict__ h0b1, unsigned short* __restrict__ h1b1,
                       float* __restrict__ h0f, float* __restrict__ c0f,
                       float* __restrict__ h1f, float* __restrict__ c1f) {
  int blk = blockIdx.x;
  if (blk < 11152) {   // transpose jobs
    const float* src; unsigned short* dst; int R, C, bx, by;
    if (blk < 1024)      { src = W_in;             dst = Win_t;  R = 2048; C = 512;   bx = blk & 15; by = blk >> 4; }
    else if (blk < 2048) { int b2 = blk - 1024; src = W0;              dst = W0e_t;  R = 512;  C = 2048;  bx = b2 & 63; by = b2 >> 6; }
    else if (blk < 3072) { int b2 = blk - 2048; src = W0 + 512 * 2048; dst = W0m_t;  R = 512;  C = 2048;  bx = b2 & 63; by = b2 >> 6; }
    else if (blk < 4096) { int b2 = blk - 3072; src = W0 + 1024 * 2048; dst = W0h_t; R = 512;  C = 2048;  bx = b2 & 63; by = b2 >> 6; }
    else if (blk < 6144) { int b2 = blk - 4096; src = W1;              dst = W1_t;   R = 1024; C = 2048;  bx = b2 & 63; by = b2 >> 6; }
    else                 { int b2 = blk - 6144; src = W_out;           dst = Wout_t; R = 512;  C = 10000; bx = b2 % 313; by = b2 / 313; }
    __shared__ float tile[32][33];
    int c0 = bx * 32, r0 = by * 32;
    int tx = threadIdx.x, ty = threadIdx.y;
#pragma unroll
    for (int i = 0; i < 4; i++) {
      int r = r0 + ty + i * 8, c = c0 + tx;
      if (r < R && c < C) tile[ty + i * 8][tx] = src[(size_t)r * C + c];
    }
    __syncthreads();
#pragma unroll
    for (int i = 0; i < 4; i++) {
      int c = c0 + ty + i * 8, r = r0 + tx;
      if (r < R && c < C) dst[(size_t)c * R + r] = f2bf(tile[tx][ty + i * 8]);
    }
    return;
  }
  int ft = threadIdx.y * 32 + threadIdx.x;
  if (blk < 11408) {        // cnn fp32 -> bf16 (65536 float4s)
    int i = (blk - 11152) * 256 + ft;
    float4 v = ((const float4*)cnn)[i];
    ushort4 p; p.x = f2bf(v.x); p.y = f2bf(v.y); p.z = f2bf(v.z); p.w = f2bf(v.w);
    ((ushort4*)cnn_b)[i] = p;
  } else if (blk < 13456) { // embedding gather (524288 float4s)
    int i = (blk - 11408) * 256 + ft;
    int r = i >> 7, k4 = (i & 127) * 4;
    int b = r & 127, t = r >> 7;
    int tk = tok[b * 32 + t];
    float4 v = *(const float4*)(emb + (size_t)tk * 512 + k4);
    ushort4 p; p.x = f2bf(v.x); p.y = f2bf(v.y); p.z = f2bf(v.z); p.w = f2bf(v.w);
    ((ushort4*)Xe)[i] = p;
  } else {                  // init h/c state (65536)
    int i = (blk - 13456) * 256 + ft;
    int b = i >> 9, jj = i & 511;
    float h0 = chs[b * 1024 + jj], c0v = chs[b * 1024 + 512 + jj];
    float h1 = chs[131072 + b * 1024 + jj], c1v = chs[131072 + b * 1024 + 512 + jj];
    h0f[i] = h0; c0f[i] = c0v; h1f[i] = h1; c1f[i] = c1v;
    h0b1[i] = f2bf(h0); h1b1[i] = f2bf(h1);
  }
}

// ---- generic 128x128-tile GEMM: C[M][N] = A[M][K] * Bt[N][K]^T (+epilogue) ----
// MODE 0: proc  = leaky(acc + bias) -> outB (bf16)
// MODE 1: Cf    = acc + bias        -> outF
// MODE 2: Zx    = acc + add128[m&127][n] -> outF
// MODE 3: logit = acc + bias -> out[(b*32+t)*N + n], b=m&127, t=m>>7 (N ragged)
template <int MODE>
__global__ __launch_bounds__(256, 2)
void k_gemm(const unsigned short* __restrict__ A, const unsigned short* __restrict__ Bt,
            const float* __restrict__ bias, const float* __restrict__ add128,
            float* __restrict__ outF, unsigned short* __restrict__ outB,
            int M, int N, int K) {
  __shared__ unsigned short As[4096];  // 128 x 32
  __shared__ unsigned short Bs[4096];
  int tid = threadIdx.x;
  int wave = tid >> 6, lane = tid & 63;
  int lr = lane & 15, lq = lane >> 4;
  int wm = (wave >> 1) * 64, wn = (wave & 1) * 64;
  int m0 = blockIdx.y * 128, n0 = blockIdx.x * 128;

  f4v acc[4][4];
  f4v zero = {0.0f, 0.0f, 0.0f, 0.0f};
#pragma unroll
  for (int i = 0; i < 4; i++)
#pragma unroll
    for (int j = 0; j < 4; j++) acc[i][j] = zero;

  int srow = tid >> 2, sofs = (tid & 3) * 8;
  int ar0 = m0 + srow, ar1 = ar0 + 64;
  int br0 = n0 + srow, br1 = br0 + 64;
  if (br0 >= N) br0 = N - 1;   // ragged-N clamp (logits); masked in epilogue
  if (br1 >= N) br1 = N - 1;
  const unsigned short* Ag0 = A + (size_t)ar0 * K + sofs;
  const unsigned short* Ag1 = A + (size_t)ar1 * K + sofs;
  const unsigned short* Bg0 = Bt + (size_t)br0 * K + sofs;
  const unsigned short* Bg1 = Bt + (size_t)br1 * K + sofs;

  for (int k0 = 0; k0 < K; k0 += 32) {
    glds16(Ag0 + k0, &As[tid * 8]);
    glds16(Ag1 + k0, &As[2048 + tid * 8]);
    glds16(Bg0 + k0, &Bs[tid * 8]);
    glds16(Bg1 + k0, &Bs[2048 + tid * 8]);
    __syncthreads();
    s8v af[4], bfr[4];
#pragma unroll
    for (int i = 0; i < 4; i++) af[i] = *(const s8v*)&As[(wm + i * 16 + lr) * 32 + lq * 8];
#pragma unroll
    for (int i = 0; i < 4; i++) bfr[i] = *(const s8v*)&Bs[(wn + i * 16 + lr) * 32 + lq * 8];
#pragma unroll
    for (int i = 0; i < 4; i++)
#pragma unroll
      for (int j = 0; j < 4; j++)
        acc[i][j] = __builtin_amdgcn_mfma_f32_16x16x32_bf16(af[i], bfr[j], acc[i][j], 0, 0, 0);
    __syncthreads();
  }

#pragma unroll
  for (int i = 0; i < 4; i++) {
#pragma unroll
    for (int j = 0; j < 4; j++) {
      int nn = n0 + wn + j * 16 + lr;       // C/D: col = lane&15
      if (nn >= N) continue;
#pragma unroll
      for (int r = 0; r < 4; r++) {
        int mm = m0 + wm + i * 16 + lq * 4 + r;  // C/D: row = (lane>>4)*4+reg
        float v = acc[i][j][r];
        if (MODE == 0) {
          v += bias[nn];
          v = v > 0.0f ? v : 0.01f * v;
          outB[(size_t)mm * N + nn] = f2bf(v);
        } else if (MODE == 1) {
          v += bias[nn];
          outF[(size_t)mm * N + nn] = v;
        } else if (MODE == 2) {
          v += add128[(size_t)(mm & 127) * N + nn];
          outF[(size_t)mm * N + nn] = v;
        } else {
          v += bias[nn];
          int b = mm & 127, t = mm >> 7;
          outF[(size_t)(b * 32 + t) * N + nn] = v;
        }
      }
    }
  }
}

// ---- recurrence phase, jt-owned blocks, LDS-resident B slice ----
// blocks 0..31: stepB(tB): z1=[h0n|h1]@W1+b1 -> h1n,c1n (+H1all), jt=bid
// blocks 32..63: stepA(tA): z0=Zx[tA]+h0@W0h -> h0n,c0n, jt=bid-32
// 256 thr = 4 waves x 2 m-tiles (16 rows each) = 8 m-tiles.
// LDS layout: sh[idx*8], idx=kc*256+g*64+ln holds
//   W[(g*512 + jt*16 + (ln&15)) * K + kc*32 + (ln>>4)*8 ..+8]  (16B)
__global__ __launch_bounds__(256, 1)
void k_phase(const unsigned short* __restrict__ W0h_t, const unsigned short* __restrict__ W1_t,
             const float* __restrict__ Zx, const float* __restrict__ b1,
             unsigned short* __restrict__ h0b0, unsigned short* __restrict__ h0b1,
             unsigned short* __restrict__ h1b0, unsigned short* __restrict__ h1b1,
             float* __restrict__ h0f, float* __restrict__ c0f,
             float* __restrict__ h1f, float* __restrict__ c1f,
             unsigned short* __restrict__ H1all,
             int tB, int doB, int tA, int doA) {
  __shared__ __align__(16) unsigned short sh[65536];   // 128 KB
  int bid = blockIdx.x;
  int tid = threadIdx.x, wave = tid >> 6, lane = tid & 63;
  int lr = lane & 15, lq = lane >> 4, lqo = lq * 8;
  int rb0 = wave * 32 + lr;
  f4v zero = {0.0f, 0.0f, 0.0f, 0.0f};

  if (bid < 32) {
    if (!doB) return;
    int jt = bid;
    // stage W1 slice (128 KB) via global_load_lds: LDS dst linear in tid
#pragma unroll
    for (int it = 0; it < 32; it++) {
      int idx = tid + it * 256;
      int kc = idx >> 8, g = (idx >> 6) & 3, ln = idx & 63;
      glds16(W1_t + (size_t)(g * 512 + jt * 16 + (ln & 15)) * 1024 + kc * 32 + (ln >> 4) * 8,
             &sh[(size_t)idx * 8]);
    }
    __syncthreads();   // drains vmcnt (global_load_lds) before LDS reads

    const unsigned short* h0r = (tB & 1) ? h0b1 : h0b0;   // h0buf[tB&1]
    const unsigned short* h1r = (tB & 1) ? h1b0 : h1b1;   // h1buf[(tB+1)&1]
    unsigned short* h1w = (tB & 1) ? h1b1 : h1b0;         // h1buf[tB&1]
    int j = jt * 16 + lr;
    float bi = b1[j], bo = b1[512 + j], bff = b1[1024 + j], bc = b1[1536 + j];
    f4v acc[2][4];
#pragma unroll
    for (int i = 0; i < 2; i++)
#pragma unroll
      for (int g = 0; g < 4; g++) acc[i][g] = zero;
    s8v a_s[8][2];    // depth-8 A ring (16 loads in flight)
    s8v b_s[4][4];    // depth-3-ahead B ring from LDS
    auto issueA = [&](int kc) {
      int kcl = kc < 32 ? kc : 31;
      int s = kc & 7;
      const unsigned short* base = (kcl < 16) ? h0r : (h1r - 512);
      const unsigned short* p = base + rb0 * 512 + kcl * 32 + lqo;
      a_s[s][0] = *(const s8v*)p;
      a_s[s][1] = *(const s8v*)(p + 8192);     // +16 rows
    };
    auto issueB = [&](int kc) {
      int kcl = kc < 32 ? kc : 31;
      int s = kc & 3;
      const unsigned short* base = &sh[kcl * 2048 + lane * 8];
      b_s[s][0] = *(const s8v*)(base);
      b_s[s][1] = *(const s8v*)(base + 512);
      b_s[s][2] = *(const s8v*)(base + 1024);
      b_s[s][3] = *(const s8v*)(base + 1536);
    };
#pragma unroll
    for (int s = 0; s < 8; s++) issueA(s);
#pragma unroll
    for (int s = 0; s < 3; s++) issueB(s);
#pragma unroll
    for (int kc = 0; kc < 32; kc++) {
      s8v a0 = a_s[kc & 7][0], a1 = a_s[kc & 7][1];
#pragma unroll
      for (int g = 0; g < 4; g++) {
        acc[0][g] = __builtin_amdgcn_mfma_f32_16x16x32_bf16(a0, b_s[kc & 3][g], acc[0][g], 0, 0, 0);
        acc[1][g] = __builtin_amdgcn_mfma_f32_16x16x32_bf16(a1, b_s[kc & 3][g], acc[1][g], 0, 0, 0);
      }
      issueB(kc + 3);
      issueA(kc + 8);
    }
#pragma unroll
    for (int i = 0; i < 2; i++)
#pragma unroll
      for (int r = 0; r < 4; r++) {
        int mm = wave * 32 + i * 16 + lq * 4 + r;
        int idx = mm * 512 + j;
        float cprev = c1f[idx];
        float iv = sigm(acc[i][0][r] + bi);
        float ov = sigm(acc[i][1][r] + bo);
        float fv = sigm(acc[i][2][r] + bff);
        float cv = tanh_(acc[i][3][r] + bc);
        float cn = fv * cprev + iv * cv;
        float hn = ov * tanh_(cn);
        c1f[idx] = cn; h1f[idx] = hn;
        unsigned short hb = f2bf(hn);
        h1w[idx] = hb;
        H1all[(size_t)(tB * 128 + mm) * 512 + j] = hb;
      }
  } else {
    if (!doA) return;
    int jt = bid - 32;
    // stage W0h slice (64 KB)
#pragma unroll
    for (int it = 0; it < 16; it++) {
      int idx = tid + it * 256;
      int kc = idx >> 8, g = (idx >> 6) & 3, ln = idx & 63;
      glds16(W0h_t + (size_t)(g * 512 + jt * 16 + (ln & 15)) * 512 + kc * 32 + (ln >> 4) * 8,
             &sh[(size_t)idx * 8]);
    }
    // prefetch Zx while staging is in flight (independent, read-only)
    int j = jt * 16 + lr;
    float zx[2][4][4];
    const float* zb = Zx + (size_t)tA * 262144 + j;
#pragma unroll
    for (int i = 0; i < 2; i++)
#pragma unroll
      for (int g = 0; g < 4; g++)
#pragma unroll
        for (int r = 0; r < 4; r++)
          zx[i][g][r] = zb[(wave * 32 + i * 16 + lq * 4 + r) * 2048 + g * 512];
    __syncthreads();   // drains vmcnt before LDS reads

    const unsigned short* h0r = (tA & 1) ? h0b0 : h0b1;   // h0buf[(tA+1)&1]
    unsigned short* h0w = (tA & 1) ? h0b1 : h0b0;         // h0buf[tA&1]
    f4v acc[2][4];
#pragma unroll
    for (int i = 0; i < 2; i++)
#pragma unroll
      for (int g = 0; g < 4; g++) acc[i][g] = zero;
    s8v a_s[8][2];
    s8v b_s[4][4];
    auto issueA = [&](int kc) {
      int kcl = kc < 16 ? kc : 15;
      int s = kc & 7;
      const unsigned short* p = h0r + rb0 * 512 + kcl * 32 + lqo;
      a_s[s][0] = *(const s8v*)p;
      a_s[s][1] = *(const s8v*)(p + 8192);
    };
    auto issueB = [&](int kc) {
      int kcl = kc < 16 ? kc : 15;
      int s = kc & 3;
      const unsigned short* base = &sh[kcl * 2048 + lane * 8];
      b_s[s][0] = *(const s8v*)(base);
      b_s[s][1] = *(const s8v*)(base + 512);
      b_s[s][2] = *(const s8v*)(base + 1024);
      b_s[s][3] = *(const s8v*)(base + 1536);
    };
#pragma unroll
    for (int s = 0; s < 8; s++) issueA(s);
#pragma unroll
    for (int s = 0; s < 3; s++) issueB(s);
#pragma unroll
    for (int kc = 0; kc < 16; kc++) {
      s8v a0 = a_s[kc & 7][0], a1 = a_s[kc & 7][1];
#pragma unroll
      for (int g = 0; g < 4; g++) {
        acc[0][g] = __builtin_amdgcn_mfma_f32_16x16x32_bf16(a0, b_s[kc & 3][g], acc[0][g], 0, 0, 0);
        acc[1][g] = __builtin_amdgcn_mfma_f32_16x16x32_bf16(a1, b_s[kc & 3][g], acc[1][g], 0, 0, 0);
      }
      issueB(kc + 3);
      issueA(kc + 8);
    }
#pragma unroll
    for (int i = 0; i < 2; i++)
#pragma unroll
      for (int r = 0; r < 4; r++) {
        int mm = wave * 32 + i * 16 + lq * 4 + r;
        int idx = mm * 512 + j;
        float cprev = c0f[idx];
        float iv = sigm(acc[i][0][r] + zx[i][0][r]);
        float ov = sigm(acc[i][1][r] + zx[i][1][r]);
        float fv = sigm(acc[i][2][r] + zx[i][2][r]);
        float cv = tanh_(acc[i][3][r] + zx[i][3][r]);
        float cn = fv * cprev + iv * cv;
        float hn = ov * tanh_(cn);
        c0f[idx] = cn; h0f[idx] = hn;
        h0w[idx] = f2bf(hn);
      }
  }
}

// ---- final hidden writeout: out[40960000 + (l*128+b)*1024 + j] ----
__global__ void k_write_hidden(const float* __restrict__ h0f, const float* __restrict__ c0f,
                               const float* __restrict__ h1f, const float* __restrict__ c1f,
                               float* __restrict__ out) {
  int idx = blockIdx.x * 256 + threadIdx.x;  // 262144
  int l = idx >> 17, rem = idx & 131071, b = rem >> 10, j = rem & 1023;
  const float* hs = l ? h1f : h0f;
  const float* cs = l ? c1f : c0f;
  float v = (j < 512) ? hs[b * 512 + j] : cs[b * 512 + (j - 512)];
  out[40960000 + idx] = v;
}

extern "C" void kernel_launch(void* const* d_in, const int* in_sizes, int n_in,
                              void* d_out, int out_size, void* d_ws, size_t ws_size,
                              hipStream_t stream) {
  const float* cnn  = (const float*)d_in[0];
  const int*   tok  = (const int*)d_in[1];
  const float* chs  = (const float*)d_in[2];
  const float* emb  = (const float*)d_in[3];
  const float* W_in = (const float*)d_in[4];
  const float* b_in = (const float*)d_in[5];
  const float* W0   = (const float*)d_in[6];
  const float* b0   = (const float*)d_in[7];
  const float* W1   = (const float*)d_in[8];
  const float* b1   = (const float*)d_in[9];
  const float* W_out= (const float*)d_in[10];
  const float* b_out= (const float*)d_in[11];
  float* out = (float*)d_out;

  char* p = (char*)d_ws;
  auto alloc = [&](size_t bytes) { char* q = p; p += (bytes + 255) & ~(size_t)255; return q; };
  unsigned short* Win_t  = (unsigned short*)alloc((size_t)512 * 2048 * 2);
  unsigned short* W0e_t  = (unsigned short*)alloc((size_t)2048 * 512 * 2);
  unsigned short* W0m_t  = (unsigned short*)alloc((size_t)2048 * 512 * 2);
  unsigned short* W0h_t  = (unsigned short*)alloc((size_t)2048 * 512 * 2);
  unsigned short* W1_t   = (unsigned short*)alloc((size_t)2048 * 1024 * 2);
  unsigned short* Wout_t = (unsigned short*)alloc((size_t)10000 * 512 * 2);
  unsigned short* cnn_b  = (unsigned short*)alloc((size_t)128 * 2048 * 2);
  unsigned short* proc_b = (unsigned short*)alloc((size_t)128 * 512 * 2);
  float*          Cf     = (float*)alloc((size_t)128 * 2048 * 4);
  unsigned short* Xe     = (unsigned short*)alloc((size_t)4096 * 512 * 2);
  float*          Zx     = (float*)alloc((size_t)4096 * 2048 * 4);
  unsigned short* h0b0   = (unsigned short*)alloc(65536 * 2);
  unsigned short* h0b1   = (unsigned short*)alloc(65536 * 2);
  unsigned short* h1b0   = (unsigned short*)alloc(65536 * 2);
  unsigned short* h1b1   = (unsigned short*)alloc(65536 * 2);
  float*          h0f    = (float*)alloc(65536 * 4);
  float*          c0f    = (float*)alloc(65536 * 4);
  float*          h1f    = (float*)alloc(65536 * 4);
  float*          c1f    = (float*)alloc(65536 * 4);
  unsigned short* H1all  = (unsigned short*)alloc((size_t)4096 * 512 * 2);

  // 1) all pre-work in one launch
  k_prep<<<13712, dim3(32, 8), 0, stream>>>(W_in, W0, W1, W_out, cnn, emb, tok, chs,
                                            Win_t, W0e_t, W0m_t, W0h_t, W1_t, Wout_t,
                                            cnn_b, Xe, h0b1, h1b1, h0f, c0f, h1f, c1f);
  // 2) proc = leaky(cnn @ W_in + b_in)
  k_gemm<0><<<dim3(4, 1), 256, 0, stream>>>(cnn_b, Win_t, b_in, nullptr, nullptr, proc_b,
                                            128, 512, 2048);
  // 3) Cf = proc @ W0[512:1024] + b0
  k_gemm<1><<<dim3(16, 1), 256, 0, stream>>>(proc_b, W0m_t, b0, nullptr, Cf, nullptr,
                                             128, 2048, 512);
  // 4) Zx[t*128+b] = emb_t @ W0[0:512] + Cf[b]
  k_gemm<2><<<dim3(16, 32), 256, 0, stream>>>(Xe, W0e_t, nullptr, Cf, Zx, nullptr,
                                              4096, 2048, 512);
  // 5) recurrence: stepA(0), then [stepB(t) || stepA(t+1)] for t=0..31
  k_phase<<<64, 256, 0, stream>>>(W0h_t, W1_t, Zx, b1, h0b0, h0b1, h1b0, h1b1,
                                  h0f, c0f, h1f, c1f, H1all, 0, 0, 0, 1);
  for (int t = 0; t < 32; t++)
    k_phase<<<64, 256, 0, stream>>>(W0h_t, W1_t, Zx, b1, h0b0, h0b1, h1b0, h1b1,
                                    h0f, c0f, h1f, c1f, H1all, t, 1, t + 1, (t < 31) ? 1 : 0);
  // 6) logits = H1all @ W_out + b_out  -> d_out[(b*32+t)*10000 + v]
  k_gemm<3><<<dim3(79, 32), 256, 0, stream>>>(H1all, Wout_t, b_out, nullptr, out, nullptr,
                                              4096, 10000, 512);
  // 7) hidden-state writeout
  k_write_hidden<<<1024, 256, 0, stream>>>(h0f, c0f, h1f, c1f, out);
}